// Round 4
// baseline (466.972 us; speedup 1.0000x reference)
//
#include <hip/hip_runtime.h>
#include <hip/hip_bf16.h>
#include <stdint.h>

// y[b,m,n] = sum_k mask64(a)[b,m,k] * b[b,k,n];  a,b fp32 [8,2048,2048].
// Pipeline: (1) merged convert kernel: A -> bf16 (64x64 activity mask,
// wave-per-tile, no LDS), B -> bf16 transposed Bt[b,n,k] via LDS; (2) bf16
// MFMA GEMM, 256x256 tile, BK=64, 8 waves, m201-geometry LDS (128B rows,
// st_16x32-class swizzle), 4 phases/K-tile, single pre-MFMA barrier/phase,
// counted vmcnt (never 0 in main loop), setprio(1) around MFMA clusters.

#define NBATCH 8
#define MDIM 2048
#define NDIM 2048
#define KDIM 2048
#define THRESH 1e-6f
#define ROWB 64  // ushorts per LDS row = 128 B (full BK row, m201 geometry)

typedef __attribute__((ext_vector_type(8))) __bf16 bf16x8;
typedef __attribute__((ext_vector_type(4))) float floatx4;
typedef __attribute__((ext_vector_type(8))) unsigned short ushort8v;

__device__ __forceinline__ unsigned short f2bf(float x) {
  union { float f; uint32_t u; } un; un.f = x;
  uint32_t u = un.u;
  return (unsigned short)((u + 0x7FFFu + ((u >> 16) & 1u)) >> 16);  // RNE
}

// ---------------- Kernel 1: merged convert (unchanged from round 2).
// z in 0..7: A path (y<8 only): wave-per-64x64-tile prescan+convert, no LDS.
// z in 8..15: B path: fp32->bf16 transpose via LDS, Bt[b,n,k] out.
// grid (32, 32, 16), block 256.
__global__ __launch_bounds__(256) void convert_ab(
    const float* __restrict__ A, const float* __restrict__ B,
    unsigned short* __restrict__ Ab, unsigned short* __restrict__ Bt) {
  __shared__ float tileS[64][65];
  const int t = threadIdx.x;
  const int z = blockIdx.z;

  if (z < 8) {
    // ---- A path: block = 4 waves = 4 tiles; wave handles one 64x64 tile.
    if (blockIdx.y >= 8) return;
    const int tk = blockIdx.x;                      // k-tile 0..31
    const int wave = t >> 6, lane = t & 63;
    const int tm = blockIdx.y * 4 + wave;           // m-tile 0..31
    const int b = z;
    const int rl = lane >> 3;                       // row-in-group 0..7
    const int c8 = (lane & 7) << 3;                 // col 0..56 step 8

    const float* base =
        A + ((size_t)b * MDIM + tm * 64) * (size_t)KDIM + tk * 64;

    float4 v[8][2];
    float mx = 0.f;
#pragma unroll
    for (int i = 0; i < 8; i++) {
      const float* p = base + (size_t)(rl + i * 8) * KDIM + c8;
      v[i][0] = *(const float4*)(p);
      v[i][1] = *(const float4*)(p + 4);
#pragma unroll
      for (int h = 0; h < 2; h++)
        mx = fmaxf(mx,
                   fmaxf(fmaxf(fabsf(v[i][h].x), fabsf(v[i][h].y)),
                         fmaxf(fabsf(v[i][h].z), fabsf(v[i][h].w))));
    }
    // Wave-wide butterfly max (all lanes end with the tile max).
#pragma unroll
    for (int off = 1; off < 64; off <<= 1)
      mx = fmaxf(mx, __shfl_xor(mx, off, 64));
    const bool active = mx > THRESH;

    unsigned short* ob =
        Ab + ((size_t)b * MDIM + tm * 64) * (size_t)KDIM + tk * 64;
#pragma unroll
    for (int i = 0; i < 8; i++) {
      ushort8v o;
      if (active) {
        o[0] = f2bf(v[i][0].x); o[1] = f2bf(v[i][0].y);
        o[2] = f2bf(v[i][0].z); o[3] = f2bf(v[i][0].w);
        o[4] = f2bf(v[i][1].x); o[5] = f2bf(v[i][1].y);
        o[6] = f2bf(v[i][1].z); o[7] = f2bf(v[i][1].w);
      } else {
#pragma unroll
        for (int j = 0; j < 8; j++) o[j] = 0;
      }
      *(ushort8v*)(ob + (size_t)(rl + i * 8) * KDIM + c8) = o;  // 16 B store
    }
  } else {
    // ---- B path: 64x64 transpose tile, Bt[b,n,k] = B[b,k,n]. (unchanged)
    const int tn = blockIdx.x, tk = blockIdx.y, b = z - 8;
    const float* base =
        B + ((size_t)b * KDIM + tk * 64) * (size_t)NDIM + tn * 64;
#pragma unroll
    for (int i = 0; i < 4; i++) {
      int e = i * 256 + t;
      int r = e >> 4, c4 = (e & 15) << 2;  // r = local k, c4 = local n
      float4 v = *(const float4*)(base + (size_t)r * NDIM + c4);
      tileS[r][c4 + 0] = v.x; tileS[r][c4 + 1] = v.y;
      tileS[r][c4 + 2] = v.z; tileS[r][c4 + 3] = v.w;
    }
    __syncthreads();

    unsigned short* ob =
        Bt + ((size_t)b * NDIM + tn * 64) * (size_t)KDIM + tk * 64;
#pragma unroll
    for (int i = 0; i < 2; i++) {
      int e = i * 256 + t;
      int rn = e >> 3, kc8 = (e & 7) << 3;  // rn = local n, kc8 = local k
      ushort8v o;
#pragma unroll
      for (int j = 0; j < 8; j++) o[j] = f2bf(tileS[kc8 + j][rn]);
      *(ushort8v*)(ob + (size_t)rn * KDIM + kc8) = o;  // 16 B store
    }
  }
}

// ---------------- Kernel 2: bf16 MFMA GEMM, C = A(MxK) * Bt(NxK)^T
// 256x256 tile, BK=64, 8 waves (2Mx4N), per-wave 128x64 output = acc[8][4].
// LDS per operand: [2 buf][256 rows][64 k] bf16; row = 128 B (full bank
// space -> m201 geometry). Swizzle (st_16x32 class): 16B-chunk c of row r
// lives at slot c ^ (((r>>2)&1)<<1); realized via inverse-swizzled global
// SOURCE (global_load_lds dest stays linear base+lane*16, rule 21), reads
// XOR the same involution. Stage unit = 64-row quarter = 8 KiB = exactly one
// global_load_lds x512 lanes.
//
// Per K-tile t (phases by (mi-half h, kk)); all stages -> OTHER buf (t+1),
// whose old data (t-1) died at t-1's group-end barrier => race-free:
//   ph0 (h0,kk0; rd A 4 + B kk0 4) stage B-q0,q1(t+1)
//   ph1 (h1,kk0; rd A 4)           stage B-q2,q3(t+1); vmcnt(4) pre-barrier
//   ph2 (h0,kk1; rd A 4 + B kk1 4) stage A-q0,q2(t+1)
//   ph3 (h1,kk1; rd A 4)           stage A-q1,q3(t+1)
//   end: vmcnt(2) (leaves A-q1,q3(t+1) in flight); s_barrier.
// Deadlines: B-q*/A-q0,q2(t+1) needed at t+1 ph0 -> covered by group-end
// vmcnt(2)+barrier. A-q1,q3(t+1) needed at t+1 ph2 -> covered by t+1 ph1's
// vmcnt(4)+barrier (6 outstanding there; oldest 2 are A-q1,q3).
#define ASYNC_COPY16(gptr, lptr)                                               \
  __builtin_amdgcn_global_load_lds(                                            \
      (const __attribute__((address_space(1))) void*)(gptr),                   \
      (__attribute__((address_space(3))) void*)(lptr), 16, 0, 0)

__device__ __forceinline__ void stage_q(const unsigned short* __restrict__ g,
                                        unsigned short* l, int tid) {
  // One quarter: 64 rows x 64 k bf16 = 8 KiB = 512 x 16B chunks, 1/thread.
  const int rl = tid >> 3;                       // local row 0..63
  const int cp = tid & 7;                        // LDS slot
  const int c = cp ^ ((((rl) >> 2) & 1) << 1);   // inverse-swizzled source
  ASYNC_COPY16(g + (size_t)rl * KDIM + c * 8, l + (size_t)tid * 8);
}

template <bool STG, bool FINAL>
__device__ __forceinline__ void do_tile(
    const unsigned short* __restrict__ Ac, const unsigned short* __restrict__ Bc,
    unsigned short* __restrict__ Ao, unsigned short* __restrict__ Bo,
    const unsigned short* __restrict__ Agl, const unsigned short* __restrict__ Bgl,
    int tid, int wm, int wn, int r16, int quad, int sw, floatx4 (&acc)[8][4]) {
  bf16x8 af[4], bq[2][4];
  const int ca0 = (quad ^ sw) * 8;        // kk=0 swizzled chunk byte offset/2
  const int ca1 = ((4 + quad) ^ sw) * 8;  // kk=1

  // ---- phase 0: (h=0, kk=0) + B kk0 frags; stage B-q0,q1(t+1).
#pragma unroll
  for (int m = 0; m < 4; m++)
    af[m] = *(const bf16x8*)(Ac + (size_t)(wm + m * 16 + r16) * ROWB + ca0);
#pragma unroll
  for (int n = 0; n < 4; n++)
    bq[0][n] = *(const bf16x8*)(Bc + (size_t)(wn + n * 16 + r16) * ROWB + ca0);
  if (STG) {
    stage_q(Bgl + (size_t)(0 * 64) * KDIM, Bo + 0 * 4096, tid);
    stage_q(Bgl + (size_t)(1 * 64) * KDIM, Bo + 1 * 4096, tid);
  }
  __builtin_amdgcn_s_barrier();
  asm volatile("s_waitcnt lgkmcnt(0)" ::: "memory");
  __builtin_amdgcn_sched_barrier(0);
  __builtin_amdgcn_s_setprio(1);
#pragma unroll
  for (int m = 0; m < 4; m++)
#pragma unroll
    for (int n = 0; n < 4; n++)
      acc[m][n] = __builtin_amdgcn_mfma_f32_16x16x32_bf16(af[m], bq[0][n],
                                                          acc[m][n], 0, 0, 0);
  __builtin_amdgcn_s_setprio(0);

  // ---- phase 1: (h=1, kk=0); stage B-q2,q3(t+1); vmcnt publishes A-q1,q3(t).
#pragma unroll
  for (int m = 0; m < 4; m++)
    af[m] =
        *(const bf16x8*)(Ac + (size_t)(wm + 64 + m * 16 + r16) * ROWB + ca0);
  if (STG) {
    stage_q(Bgl + (size_t)(2 * 64) * KDIM, Bo + 2 * 4096, tid);
    stage_q(Bgl + (size_t)(3 * 64) * KDIM, Bo + 3 * 4096, tid);
    asm volatile("s_waitcnt vmcnt(4)" ::: "memory");  // A-q1,q3(t) landed
  } else {
    asm volatile("s_waitcnt vmcnt(0)" ::: "memory");  // final tile drain
  }
  __builtin_amdgcn_s_barrier();
  asm volatile("s_waitcnt lgkmcnt(0)" ::: "memory");
  __builtin_amdgcn_sched_barrier(0);
  __builtin_amdgcn_s_setprio(1);
#pragma unroll
  for (int m = 0; m < 4; m++)
#pragma unroll
    for (int n = 0; n < 4; n++)
      acc[4 + m][n] = __builtin_amdgcn_mfma_f32_16x16x32_bf16(
          af[m], bq[0][n], acc[4 + m][n], 0, 0, 0);
  __builtin_amdgcn_s_setprio(0);

  // ---- phase 2: (h=0, kk=1) + B kk1 frags; stage A-q0,q2(t+1).
#pragma unroll
  for (int m = 0; m < 4; m++)
    af[m] = *(const bf16x8*)(Ac + (size_t)(wm + m * 16 + r16) * ROWB + ca1);
#pragma unroll
  for (int n = 0; n < 4; n++)
    bq[1][n] = *(const bf16x8*)(Bc + (size_t)(wn + n * 16 + r16) * ROWB + ca1);
  if (STG) {
    stage_q(Agl + (size_t)(0 * 64) * KDIM, Ao + 0 * 4096, tid);
    stage_q(Agl + (size_t)(2 * 64) * KDIM, Ao + 2 * 4096, tid);
  }
  __builtin_amdgcn_s_barrier();
  asm volatile("s_waitcnt lgkmcnt(0)" ::: "memory");
  __builtin_amdgcn_sched_barrier(0);
  __builtin_amdgcn_s_setprio(1);
#pragma unroll
  for (int m = 0; m < 4; m++)
#pragma unroll
    for (int n = 0; n < 4; n++)
      acc[m][n] = __builtin_amdgcn_mfma_f32_16x16x32_bf16(af[m], bq[1][n],
                                                          acc[m][n], 0, 0, 0);
  __builtin_amdgcn_s_setprio(0);

  // ---- phase 3: (h=1, kk=1); stage A-q1,q3(t+1).
#pragma unroll
  for (int m = 0; m < 4; m++)
    af[m] =
        *(const bf16x8*)(Ac + (size_t)(wm + 64 + m * 16 + r16) * ROWB + ca1);
  if (STG) {
    stage_q(Agl + (size_t)(1 * 64) * KDIM, Ao + 1 * 4096, tid);
    stage_q(Agl + (size_t)(3 * 64) * KDIM, Ao + 3 * 4096, tid);
  }
  __builtin_amdgcn_s_barrier();
  asm volatile("s_waitcnt lgkmcnt(0)" ::: "memory");
  __builtin_amdgcn_sched_barrier(0);
  __builtin_amdgcn_s_setprio(1);
#pragma unroll
  for (int m = 0; m < 4; m++)
#pragma unroll
    for (int n = 0; n < 4; n++)
      acc[4 + m][n] = __builtin_amdgcn_mfma_f32_16x16x32_bf16(
          af[m], bq[1][n], acc[4 + m][n], 0, 0, 0);
  __builtin_amdgcn_s_setprio(0);

  if (!FINAL) {
    asm volatile("s_waitcnt vmcnt(2)" ::: "memory");  // keep A-q1,q3(t+1)
    __builtin_amdgcn_s_barrier();                     // in flight
  }
}

__global__ __launch_bounds__(512, 2) void gemm_bf16_8ph(
    const unsigned short* __restrict__ A, const unsigned short* __restrict__ Bt,
    float* __restrict__ C) {
  // [buf][256 rows][64 k] each; A 64 KiB + B 64 KiB = 128 KiB (1 block/CU).
  __shared__ __align__(16) unsigned short AsL[2 * 16384];
  __shared__ __align__(16) unsigned short BsL[2 * 16384];

  const int tid = threadIdx.x;
  const int lane = tid & 63, wave = tid >> 6;
  const int r16 = lane & 15, quad = lane >> 4;
  const int sw = ((r16 >> 2) & 1) << 1;  // st_16x32-class read swizzle key

  // XCD-aware swizzle: id&7 -> batch (one per XCD); within batch 8x8 tiles,
  // 2x2 supertiles of 4x4, snake.
  const int id = blockIdx.x;
  const int bb = id & 7;
  const int j = id >> 3;          // 0..63
  const int st = j >> 4;          // 0..3
  const int w = j & 15;
  const int str = st >> 1;
  int stc = st & 1;
  if (str & 1) stc ^= 1;
  const int bm = str * 4 + (w >> 2);
  const int bn = stc * 4 + (w & 3);

  const int wr = wave >> 2, wc = wave & 3;
  const int wm = wr * 128, wn = wc * 64;

  const unsigned short* Abase =
      A + (size_t)bb * MDIM * KDIM + (size_t)(bm * 256) * KDIM;
  const unsigned short* Bbase =
      Bt + (size_t)bb * NDIM * KDIM + (size_t)(bn * 256) * KDIM;

  floatx4 acc[8][4];
#pragma unroll
  for (int i = 0; i < 8; i++)
#pragma unroll
    for (int n = 0; n < 4; n++) acc[i][n] = (floatx4){0.f, 0.f, 0.f, 0.f};

  // Prologue: tile0's 8 quarters -> buf0, ordered so vmcnt(2) completes the
  // 6 needed at ph0 (B-q0..3, A-q0,q2) and leaves A-q1,q3 in flight.
  stage_q(Bbase + (size_t)(0 * 64) * KDIM, BsL + 0 * 4096, tid);
  stage_q(Bbase + (size_t)(1 * 64) * KDIM, BsL + 1 * 4096, tid);
  stage_q(Bbase + (size_t)(2 * 64) * KDIM, BsL + 2 * 4096, tid);
  stage_q(Bbase + (size_t)(3 * 64) * KDIM, BsL + 3 * 4096, tid);
  stage_q(Abase + (size_t)(0 * 64) * KDIM, AsL + 0 * 4096, tid);
  stage_q(Abase + (size_t)(2 * 64) * KDIM, AsL + 2 * 4096, tid);
  stage_q(Abase + (size_t)(1 * 64) * KDIM, AsL + 1 * 4096, tid);
  stage_q(Abase + (size_t)(3 * 64) * KDIM, AsL + 3 * 4096, tid);
  asm volatile("s_waitcnt vmcnt(2)" ::: "memory");
  __builtin_amdgcn_s_barrier();

  // Main loop: tiles 0..29 (two tiles per iteration, buffers alternate).
  for (int it = 0; it < 15; it++) {
    const int t = it * 2;
    do_tile<true, false>(AsL, BsL, AsL + 16384, BsL + 16384,
                         Abase + (t + 1) * 64, Bbase + (t + 1) * 64, tid, wm,
                         wn, r16, quad, sw, acc);
    do_tile<true, false>(AsL + 16384, BsL + 16384, AsL, BsL,
                         Abase + (t + 2) * 64, Bbase + (t + 2) * 64, tid, wm,
                         wn, r16, quad, sw, acc);
  }
  // Tile 30: stages tile 31 -> buf1 normally.
  do_tile<true, false>(AsL, BsL, AsL + 16384, BsL + 16384, Abase + 31 * 64,
                       Bbase + 31 * 64, tid, wm, wn, r16, quad, sw, acc);
  // Tile 31: no stages; ph1 drains vmcnt(0); no group-end barrier.
  do_tile<false, true>(AsL + 16384, BsL + 16384, AsL, BsL, Abase, Bbase, tid,
                       wm, wn, r16, quad, sw, acc);

  // Epilogue: D layout col = lane&15, row = quad*4 + reg (m89/m91-verified).
  float* Cb = C + (size_t)bb * MDIM * NDIM;
  const int colBase = bn * 256 + wn + r16;
  const int rowBase = bm * 256 + wm + quad * 4;
#pragma unroll
  for (int mi = 0; mi < 8; mi++) {
#pragma unroll
    for (int ni = 0; ni < 4; ni++) {
      int col = colBase + ni * 16;
      int row = rowBase + mi * 16;
#pragma unroll
      for (int r = 0; r < 4; r++)
        Cb[(size_t)(row + r) * NDIM + col] = acc[mi][ni][r];
    }
  }
}

// ---------------- Fallback: fp32 LDS-tiled GEMM (only if ws too small).
__global__ __launch_bounds__(256) void gemm_f32_fallback(
    const float* __restrict__ A, const float* __restrict__ B,
    float* __restrict__ C) {
  __shared__ float As[64][65];
  __shared__ float Bs[64][65];
  const int tid = threadIdx.x;
  const int tx = tid & 15, ty = tid >> 4;
  const int bn = blockIdx.x, bm = blockIdx.y, bb = blockIdx.z;
  const float* Ab = A + (size_t)bb * MDIM * KDIM + (size_t)(bm * 64) * KDIM;
  const float* Bb = B + (size_t)bb * KDIM * NDIM + bn * 64;

  float acc[4][4] = {};
  for (int k0 = 0; k0 < KDIM; k0 += 64) {
#pragma unroll
    for (int i = 0; i < 4; i++) {
      int e = i * 256 + tid;
      int r = e >> 4, c4 = (e & 15) << 2;
      float4 va = *(const float4*)(Ab + (size_t)r * KDIM + k0 + c4);
      As[r][c4] = va.x; As[r][c4 + 1] = va.y;
      As[r][c4 + 2] = va.z; As[r][c4 + 3] = va.w;
      float4 vb = *(const float4*)(Bb + (size_t)(k0 + r) * NDIM + c4);
      Bs[r][c4] = vb.x; Bs[r][c4 + 1] = vb.y;
      Bs[r][c4 + 2] = vb.z; Bs[r][c4 + 3] = vb.w;
    }
    __syncthreads();
    for (int kk = 0; kk < 64; kk++) {
      float a0[4], b0[4];
#pragma unroll
      for (int i = 0; i < 4; i++) a0[i] = As[ty + 16 * i][kk];
#pragma unroll
      for (int jx = 0; jx < 4; jx++) b0[jx] = Bs[kk][tx + 16 * jx];
#pragma unroll
      for (int i = 0; i < 4; i++)
#pragma unroll
        for (int jx = 0; jx < 4; jx++) acc[i][jx] += a0[i] * b0[jx];
    }
    __syncthreads();
  }
  float* Cb = C + (size_t)bb * MDIM * NDIM;
#pragma unroll
  for (int i = 0; i < 4; i++)
#pragma unroll
    for (int jx = 0; jx < 4; jx++)
      Cb[(size_t)(bm * 64 + ty + 16 * i) * NDIM + bn * 64 + tx + 16 * jx] =
          acc[i][jx];
}

extern "C" void kernel_launch(void* const* d_in, const int* in_sizes, int n_in,
                              void* d_out, int out_size, void* d_ws,
                              size_t ws_size, hipStream_t stream) {
  const float* a = (const float*)d_in[0];
  const float* b = (const float*)d_in[1];
  float* out = (float*)d_out;

  const size_t elems = (size_t)NBATCH * MDIM * KDIM;       // 33.55M
  const size_t need = 2 * elems * sizeof(unsigned short);  // 134.2 MB

  if (ws_size >= need) {
    unsigned short* abf = (unsigned short*)d_ws;
    unsigned short* btf = abf + elems;
    hipLaunchKernelGGL(convert_ab, dim3(32, 32, 16), dim3(256), 0, stream, a,
                       b, abf, btf);
    hipLaunchKernelGGL(gemm_bf16_8ph, dim3(512), dim3(512), 0, stream, abf,
                       btf, out);
  } else {
    hipLaunchKernelGGL(gemm_f32_fallback, dim3(32, 32, NBATCH), dim3(256), 0,
                       stream, a, b, out);
  }
}

// Round 6
// 456.646 us; speedup vs baseline: 1.0226x; 1.0226x over previous
//
#include <hip/hip_runtime.h>
#include <hip/hip_bf16.h>
#include <stdint.h>

// y[b,m,n] = sum_k mask64(a)[b,m,k] * b[b,k,n];  a,b fp32 [8,2048,2048].
// Pipeline: (1) merged convert kernel: A -> bf16 (64x64 activity mask,
// wave-per-tile, no LDS), B -> bf16 transposed Bt[b,n,k] via LDS; (2) bf16
// MFMA GEMM, 256x256 tile, BK=64, 8 waves, r0-geometry LDS (128B rows,
// 3-bit chunk XOR swizzle c^(r&7) -> measured ZERO bank conflicts in r0),
// 4 phases/K-tile, single pre-MFMA barrier/phase, all 8 stage units issued
// in ph0/ph1 (tile-end vmcnt(0) waits only on 2-3-phase-old loads),
// setprio(1) around MFMA clusters.

#define NBATCH 8
#define MDIM 2048
#define NDIM 2048
#define KDIM 2048
#define THRESH 1e-6f
#define ROWB 64  // ushorts per LDS row = 128 B, 8 x 16B chunks

typedef __attribute__((ext_vector_type(8))) __bf16 bf16x8;
typedef __attribute__((ext_vector_type(4))) float floatx4;
typedef __attribute__((ext_vector_type(8))) unsigned short ushort8v;

__device__ __forceinline__ unsigned short f2bf(float x) {
  union { float f; uint32_t u; } un; un.f = x;
  uint32_t u = un.u;
  return (unsigned short)((u + 0x7FFFu + ((u >> 16) & 1u)) >> 16);  // RNE
}

// ---------------- Kernel 1: merged convert (unchanged).
// z in 0..7: A path (y<8 only): wave-per-64x64-tile prescan+convert, no LDS.
// z in 8..15: B path: fp32->bf16 transpose via LDS, Bt[b,n,k] out.
// grid (32, 32, 16), block 256.
__global__ __launch_bounds__(256) void convert_ab(
    const float* __restrict__ A, const float* __restrict__ B,
    unsigned short* __restrict__ Ab, unsigned short* __restrict__ Bt) {
  __shared__ float tileS[64][65];
  const int t = threadIdx.x;
  const int z = blockIdx.z;

  if (z < 8) {
    // ---- A path: block = 4 waves = 4 tiles; wave handles one 64x64 tile.
    if (blockIdx.y >= 8) return;
    const int tk = blockIdx.x;                      // k-tile 0..31
    const int wave = t >> 6, lane = t & 63;
    const int tm = blockIdx.y * 4 + wave;           // m-tile 0..31
    const int b = z;
    const int rl = lane >> 3;                       // row-in-group 0..7
    const int c8 = (lane & 7) << 3;                 // col 0..56 step 8

    const float* base =
        A + ((size_t)b * MDIM + tm * 64) * (size_t)KDIM + tk * 64;

    float4 v[8][2];
    float mx = 0.f;
#pragma unroll
    for (int i = 0; i < 8; i++) {
      const float* p = base + (size_t)(rl + i * 8) * KDIM + c8;
      v[i][0] = *(const float4*)(p);
      v[i][1] = *(const float4*)(p + 4);
#pragma unroll
      for (int h = 0; h < 2; h++)
        mx = fmaxf(mx,
                   fmaxf(fmaxf(fabsf(v[i][h].x), fabsf(v[i][h].y)),
                         fmaxf(fabsf(v[i][h].z), fabsf(v[i][h].w))));
    }
    // Wave-wide butterfly max (all lanes end with the tile max).
#pragma unroll
    for (int off = 1; off < 64; off <<= 1)
      mx = fmaxf(mx, __shfl_xor(mx, off, 64));
    const bool active = mx > THRESH;

    unsigned short* ob =
        Ab + ((size_t)b * MDIM + tm * 64) * (size_t)KDIM + tk * 64;
#pragma unroll
    for (int i = 0; i < 8; i++) {
      ushort8v o;
      if (active) {
        o[0] = f2bf(v[i][0].x); o[1] = f2bf(v[i][0].y);
        o[2] = f2bf(v[i][0].z); o[3] = f2bf(v[i][0].w);
        o[4] = f2bf(v[i][1].x); o[5] = f2bf(v[i][1].y);
        o[6] = f2bf(v[i][1].z); o[7] = f2bf(v[i][1].w);
      } else {
#pragma unroll
        for (int j = 0; j < 8; j++) o[j] = 0;
      }
      *(ushort8v*)(ob + (size_t)(rl + i * 8) * KDIM + c8) = o;  // 16 B store
    }
  } else {
    // ---- B path: 64x64 transpose tile, Bt[b,n,k] = B[b,k,n]. (unchanged)
    const int tn = blockIdx.x, tk = blockIdx.y, b = z - 8;
    const float* base =
        B + ((size_t)b * KDIM + tk * 64) * (size_t)NDIM + tn * 64;
#pragma unroll
    for (int i = 0; i < 4; i++) {
      int e = i * 256 + t;
      int r = e >> 4, c4 = (e & 15) << 2;  // r = local k, c4 = local n
      float4 v = *(const float4*)(base + (size_t)r * NDIM + c4);
      tileS[r][c4 + 0] = v.x; tileS[r][c4 + 1] = v.y;
      tileS[r][c4 + 2] = v.z; tileS[r][c4 + 3] = v.w;
    }
    __syncthreads();

    unsigned short* ob =
        Bt + ((size_t)b * NDIM + tn * 64) * (size_t)KDIM + tk * 64;
#pragma unroll
    for (int i = 0; i < 2; i++) {
      int e = i * 256 + t;
      int rn = e >> 3, kc8 = (e & 7) << 3;  // rn = local n, kc8 = local k
      ushort8v o;
#pragma unroll
      for (int j = 0; j < 8; j++) o[j] = f2bf(tileS[kc8 + j][rn]);
      *(ushort8v*)(ob + (size_t)rn * KDIM + kc8) = o;  // 16 B store
    }
  }
}

// ---------------- Kernel 2: bf16 MFMA GEMM, C = A(MxK) * Bt(NxK)^T
// 256x256 tile, BK=64, 8 waves (2Mx4N), per-wave 128x64 output = acc[8][4].
// LDS per operand: [2 buf][256 rows][64 k] bf16; 128B rows, 8 chunks of 16B.
// Swizzle (r0-verified, conflict counter 0.0): LDS slot of global chunk c at
// row r is c ^ (r&7) -- 3-bit key spreads a 16-lane read group over 8 x 4
// banks = all 32 at <=2-way (free). Writes via inverse-swizzled global SOURCE
// (global_load_lds dest stays linear base+lane*16, rule 21), reads XOR the
// same involution: cir = (kk*4+quad) ^ (r16&7).
//
// Per K-tile t, 4 phases (mi-half h x kk), single pre-MFMA barrier each:
//   ph0 (h0,kk0; rd A 4 + B kk0 4) stage B-q0..q3(t+1) -> other buf
//   ph1 (h1,kk0; rd A 4)           stage A-q0..q3(t+1) -> other buf
//   ph2 (h0,kk1; rd A 4 + B kk1 4)
//   ph3 (h1,kk1; rd A 4)
//   end: vmcnt(0) -- all 8 outstanding loads were issued 2-3 phases
//   (~600-900 cyc) earlier, so this never waits on a fresh load; s_barrier.
// Race-freedom: stages target the OTHER buffer, dead since the previous
// tile-end barrier; all stages land before the end barrier releases reads.
#define ASYNC_COPY16(gptr, lptr)                                               \
  __builtin_amdgcn_global_load_lds(                                            \
      (const __attribute__((address_space(1))) void*)(gptr),                   \
      (__attribute__((address_space(3))) void*)(lptr), 16, 0, 0)

__device__ __forceinline__ void stage_q(const unsigned short* __restrict__ g,
                                        unsigned short* l, int tid) {
  // One quarter: 64 rows x 64 k bf16 = 8 KiB = 512 x 16B chunks, 1/thread.
  const int r = tid >> 3;                 // local row 0..63
  const int c = (tid & 7) ^ (r & 7);      // inverse-swizzled source chunk
  ASYNC_COPY16(g + (size_t)r * KDIM + c * 8, l + (size_t)tid * 8);
}

template <bool STG, bool FINAL>
__device__ __forceinline__ void do_tile(
    const unsigned short* __restrict__ Ac, const unsigned short* __restrict__ Bc,
    unsigned short* __restrict__ Ao, unsigned short* __restrict__ Bo,
    const unsigned short* __restrict__ Agl, const unsigned short* __restrict__ Bgl,
    int tid, int wm, int wn, int r16, int quad, int sw, floatx4 (&acc)[8][4]) {
  bf16x8 af[4], bq[2][4];
  const int ca0 = (quad ^ sw) * 8;        // kk=0 swizzled chunk offset (sw=r16&7)
  const int ca1 = ((4 + quad) ^ sw) * 8;  // kk=1

  // ---- phase 0: (h=0, kk=0) + B kk0 frags; stage B-q0..q3(t+1).
#pragma unroll
  for (int m = 0; m < 4; m++)
    af[m] = *(const bf16x8*)(Ac + (size_t)(wm + m * 16 + r16) * ROWB + ca0);
#pragma unroll
  for (int n = 0; n < 4; n++)
    bq[0][n] = *(const bf16x8*)(Bc + (size_t)(wn + n * 16 + r16) * ROWB + ca0);
  if (STG) {
#pragma unroll
    for (int q = 0; q < 4; q++)
      stage_q(Bgl + (size_t)(q * 64) * KDIM, Bo + q * 4096, tid);
  }
  __builtin_amdgcn_s_barrier();
  asm volatile("s_waitcnt lgkmcnt(0)" ::: "memory");
  __builtin_amdgcn_sched_barrier(0);
  __builtin_amdgcn_s_setprio(1);
#pragma unroll
  for (int m = 0; m < 4; m++)
#pragma unroll
    for (int n = 0; n < 4; n++)
      acc[m][n] = __builtin_amdgcn_mfma_f32_16x16x32_bf16(af[m], bq[0][n],
                                                          acc[m][n], 0, 0, 0);
  __builtin_amdgcn_s_setprio(0);

  // ---- phase 1: (h=1, kk=0); stage A-q0..q3(t+1).
#pragma unroll
  for (int m = 0; m < 4; m++)
    af[m] =
        *(const bf16x8*)(Ac + (size_t)(wm + 64 + m * 16 + r16) * ROWB + ca0);
  if (STG) {
#pragma unroll
    for (int q = 0; q < 4; q++)
      stage_q(Agl + (size_t)(q * 64) * KDIM, Ao + q * 4096, tid);
  }
  __builtin_amdgcn_s_barrier();
  asm volatile("s_waitcnt lgkmcnt(0)" ::: "memory");
  __builtin_amdgcn_sched_barrier(0);
  __builtin_amdgcn_s_setprio(1);
#pragma unroll
  for (int m = 0; m < 4; m++)
#pragma unroll
    for (int n = 0; n < 4; n++)
      acc[4 + m][n] = __builtin_amdgcn_mfma_f32_16x16x32_bf16(
          af[m], bq[0][n], acc[4 + m][n], 0, 0, 0);
  __builtin_amdgcn_s_setprio(0);

  // ---- phase 2: (h=0, kk=1) + B kk1 frags.
#pragma unroll
  for (int m = 0; m < 4; m++)
    af[m] = *(const bf16x8*)(Ac + (size_t)(wm + m * 16 + r16) * ROWB + ca1);
#pragma unroll
  for (int n = 0; n < 4; n++)
    bq[1][n] = *(const bf16x8*)(Bc + (size_t)(wn + n * 16 + r16) * ROWB + ca1);
  __builtin_amdgcn_s_barrier();
  asm volatile("s_waitcnt lgkmcnt(0)" ::: "memory");
  __builtin_amdgcn_sched_barrier(0);
  __builtin_amdgcn_s_setprio(1);
#pragma unroll
  for (int m = 0; m < 4; m++)
#pragma unroll
    for (int n = 0; n < 4; n++)
      acc[m][n] = __builtin_amdgcn_mfma_f32_16x16x32_bf16(af[m], bq[1][n],
                                                          acc[m][n], 0, 0, 0);
  __builtin_amdgcn_s_setprio(0);

  // ---- phase 3: (h=1, kk=1).
#pragma unroll
  for (int m = 0; m < 4; m++)
    af[m] =
        *(const bf16x8*)(Ac + (size_t)(wm + 64 + m * 16 + r16) * ROWB + ca1);
  __builtin_amdgcn_s_barrier();
  asm volatile("s_waitcnt lgkmcnt(0)" ::: "memory");
  __builtin_amdgcn_sched_barrier(0);
  __builtin_amdgcn_s_setprio(1);
#pragma unroll
  for (int m = 0; m < 4; m++)
#pragma unroll
    for (int n = 0; n < 4; n++)
      acc[4 + m][n] = __builtin_amdgcn_mfma_f32_16x16x32_bf16(
          af[m], bq[1][n], acc[4 + m][n], 0, 0, 0);
  __builtin_amdgcn_s_setprio(0);

  if (!FINAL) {
    asm volatile("s_waitcnt vmcnt(0)" ::: "memory");  // loads are 2-3 phases
    __builtin_amdgcn_s_barrier();                     // old: cheap drain
  }
}

__global__ __launch_bounds__(512, 2) void gemm_bf16_8ph(
    const unsigned short* __restrict__ A, const unsigned short* __restrict__ Bt,
    float* __restrict__ C) {
  // [buf][256 rows][64 k] each; A 64 KiB + B 64 KiB = 128 KiB (1 block/CU).
  __shared__ __align__(16) unsigned short AsL[2 * 16384];
  __shared__ __align__(16) unsigned short BsL[2 * 16384];

  const int tid = threadIdx.x;
  const int lane = tid & 63, wave = tid >> 6;
  const int r16 = lane & 15, quad = lane >> 4;
  const int sw = r16 & 7;  // 3-bit read swizzle key (r0-verified, 0 conflicts)

  // XCD-aware swizzle: id&7 -> batch (one per XCD); within batch 8x8 tiles,
  // 2x2 supertiles of 4x4, snake.
  const int id = blockIdx.x;
  const int bb = id & 7;
  const int j = id >> 3;          // 0..63
  const int st = j >> 4;          // 0..3
  const int w = j & 15;
  const int str = st >> 1;
  int stc = st & 1;
  if (str & 1) stc ^= 1;
  const int bm = str * 4 + (w >> 2);
  const int bn = stc * 4 + (w & 3);

  const int wr = wave >> 2, wc = wave & 3;
  const int wm = wr * 128, wn = wc * 64;

  const unsigned short* Abase =
      A + (size_t)bb * MDIM * KDIM + (size_t)(bm * 256) * KDIM;
  const unsigned short* Bbase =
      Bt + (size_t)bb * NDIM * KDIM + (size_t)(bn * 256) * KDIM;

  floatx4 acc[8][4];
#pragma unroll
  for (int i = 0; i < 8; i++)
#pragma unroll
    for (int n = 0; n < 4; n++) acc[i][n] = (floatx4){0.f, 0.f, 0.f, 0.f};

  // Prologue: tile0's 8 quarters -> buf0; drain (startup only).
#pragma unroll
  for (int q = 0; q < 4; q++)
    stage_q(Bbase + (size_t)(q * 64) * KDIM, BsL + q * 4096, tid);
#pragma unroll
  for (int q = 0; q < 4; q++)
    stage_q(Abase + (size_t)(q * 64) * KDIM, AsL + q * 4096, tid);
  asm volatile("s_waitcnt vmcnt(0)" ::: "memory");
  __builtin_amdgcn_s_barrier();

  // Main loop: tiles 0..29 (two tiles per iteration, buffers alternate).
  for (int it = 0; it < 15; it++) {
    const int t = it * 2;
    do_tile<true, false>(AsL, BsL, AsL + 16384, BsL + 16384,
                         Abase + (t + 1) * 64, Bbase + (t + 1) * 64, tid, wm,
                         wn, r16, quad, sw, acc);
    do_tile<true, false>(AsL + 16384, BsL + 16384, AsL, BsL,
                         Abase + (t + 2) * 64, Bbase + (t + 2) * 64, tid, wm,
                         wn, r16, quad, sw, acc);
  }
  // Tile 30: stages tile 31 -> buf1 normally.
  do_tile<true, false>(AsL, BsL, AsL + 16384, BsL + 16384, Abase + 31 * 64,
                       Bbase + 31 * 64, tid, wm, wn, r16, quad, sw, acc);
  // Tile 31: no stages; no end wait.
  do_tile<false, true>(AsL + 16384, BsL + 16384, AsL, BsL, Abase, Bbase, tid,
                       wm, wn, r16, quad, sw, acc);

  // Epilogue: D layout col = lane&15, row = quad*4 + reg (m89/m91-verified).
  float* Cb = C + (size_t)bb * MDIM * NDIM;
  const int colBase = bn * 256 + wn + r16;
  const int rowBase = bm * 256 + wm + quad * 4;
#pragma unroll
  for (int mi = 0; mi < 8; mi++) {
#pragma unroll
    for (int ni = 0; ni < 4; ni++) {
      int col = colBase + ni * 16;
      int row = rowBase + mi * 16;
#pragma unroll
      for (int r = 0; r < 4; r++)
        Cb[(size_t)(row + r) * NDIM + col] = acc[mi][ni][r];
    }
  }
}

// ---------------- Fallback: fp32 LDS-tiled GEMM (only if ws too small).
__global__ __launch_bounds__(256) void gemm_f32_fallback(
    const float* __restrict__ A, const float* __restrict__ B,
    float* __restrict__ C) {
  __shared__ float As[64][65];
  __shared__ float Bs[64][65];
  const int tid = threadIdx.x;
  const int tx = tid & 15, ty = tid >> 4;
  const int bn = blockIdx.x, bm = blockIdx.y, bb = blockIdx.z;
  const float* Ab = A + (size_t)bb * MDIM * KDIM + (size_t)(bm * 64) * KDIM;
  const float* Bb = B + (size_t)bb * KDIM * NDIM + bn * 64;

  float acc[4][4] = {};
  for (int k0 = 0; k0 < KDIM; k0 += 64) {
#pragma unroll
    for (int i = 0; i < 4; i++) {
      int e = i * 256 + tid;
      int r = e >> 4, c4 = (e & 15) << 2;
      float4 va = *(const float4*)(Ab + (size_t)r * KDIM + k0 + c4);
      As[r][c4] = va.x; As[r][c4 + 1] = va.y;
      As[r][c4 + 2] = va.z; As[r][c4 + 3] = va.w;
      float4 vb = *(const float4*)(Bb + (size_t)(k0 + r) * NDIM + c4);
      Bs[r][c4] = vb.x; Bs[r][c4 + 1] = vb.y;
      Bs[r][c4 + 2] = vb.z; Bs[r][c4 + 3] = vb.w;
    }
    __syncthreads();
    for (int kk = 0; kk < 64; kk++) {
      float a0[4], b0[4];
#pragma unroll
      for (int i = 0; i < 4; i++) a0[i] = As[ty + 16 * i][kk];
#pragma unroll
      for (int jx = 0; jx < 4; jx++) b0[jx] = Bs[kk][tx + 16 * jx];
#pragma unroll
      for (int i = 0; i < 4; i++)
#pragma unroll
        for (int jx = 0; jx < 4; jx++) acc[i][jx] += a0[i] * b0[jx];
    }
    __syncthreads();
  }
  float* Cb = C + (size_t)bb * MDIM * NDIM;
#pragma unroll
  for (int i = 0; i < 4; i++)
#pragma unroll
    for (int jx = 0; jx < 4; jx++)
      Cb[(size_t)(bm * 64 + ty + 16 * i) * NDIM + bn * 64 + tx + 16 * jx] =
          acc[i][jx];
}

extern "C" void kernel_launch(void* const* d_in, const int* in_sizes, int n_in,
                              void* d_out, int out_size, void* d_ws,
                              size_t ws_size, hipStream_t stream) {
  const float* a = (const float*)d_in[0];
  const float* b = (const float*)d_in[1];
  float* out = (float*)d_out;

  const size_t elems = (size_t)NBATCH * MDIM * KDIM;       // 33.55M
  const size_t need = 2 * elems * sizeof(unsigned short);  // 134.2 MB

  if (ws_size >= need) {
    unsigned short* abf = (unsigned short*)d_ws;
    unsigned short* btf = abf + elems;
    hipLaunchKernelGGL(convert_ab, dim3(32, 32, 16), dim3(256), 0, stream, a,
                       b, abf, btf);
    hipLaunchKernelGGL(gemm_bf16_8ph, dim3(512), dim3(512), 0, stream, abf,
                       btf, out);
  } else {
    hipLaunchKernelGGL(gemm_f32_fallback, dim3(32, 32, NBATCH), dim3(256), 0,
                       stream, a, b, out);
  }
}